// Round 15
// baseline (378.750 us; speedup 1.0000x reference)
//
#include <hip/hip_runtime.h>

// LPKT forward. B=64, S=128, NQ=2000, C=128, K=64, DE=DC=64.
// R15: R14/R11 with one reorder — the af-read + acc/ya MFMA block moves from
// the pre-barrier tail of step t to the post-barrier head of step t+1. The
// BAR() lgkmcnt(0) drain was serializing those LDS reads with barrier arrival
// (~300-400 cy/step); post-barrier they overlap the chain-top up[] reads.

constexpr int BB = 64, SS = 128, CD = 128;
constexpr int RECF = 136;   // BASE2p[64]|BASE3p[64]|QBITS[4]|pad
constexpr int HP2  = 72;    // shorts per hsb row (144B)

typedef short bf16x8 __attribute__((ext_vector_type(8)));
typedef float f32x4  __attribute__((ext_vector_type(4)));

// barrier WITHOUT vmcnt drain: orders LDS only, global prefetches stay in flight
#define BAR() asm volatile("s_waitcnt lgkmcnt(0)\ns_barrier" ::: "memory")

__device__ __forceinline__ short f2bf(float x) {
  unsigned u = __builtin_bit_cast(unsigned, x);
  unsigned r = u + 0x7fffu + ((u >> 16) & 1u);
  return (short)(r >> 16);
}
__device__ __forceinline__ unsigned pk2bf(float a, float b) {
  unsigned ua = __builtin_bit_cast(unsigned, a);
  unsigned ub = __builtin_bit_cast(unsigned, b);
  unsigned ra = ua + 0x7fffu + ((ua >> 16) & 1u);
  unsigned rb = ub + 0x7fffu + ((ub >> 16) & 1u);
  return (ra >> 16) | (rb & 0xffff0000u);
}
__device__ __forceinline__ float sigm(float x) {
  return __builtin_amdgcn_rcpf(1.f + __expf(-x));
}
__device__ __forceinline__ void store_bf4(short* p, float a, float b, float c, float d) {
  uint2 v = {pk2bf(a, b), pk2bf(c, d)};
  *(uint2*)p = v;
}

// ---------------------------------------------------------------------------
// pcT: per-question tables (pcK folded via associativity); block 0 adds Uws.
__global__ void pcT(const float* __restrict__ Eq, const float* __restrict__ qmat,
                    const float* __restrict__ W1, const float* __restrict__ W2,
                    const float* __restrict__ W3, const float* __restrict__ Ec,
                    const float* __restrict__ b1,
                    const float* __restrict__ Wdiff, const float* __restrict__ bdiff,
                    const float* __restrict__ Wdisc, const float* __restrict__ bdisc,
                    float* __restrict__ T, float* __restrict__ DIFF,
                    float* __restrict__ DISCq, float* __restrict__ Uws) {
  int q0 = blockIdx.x * 8, tid = threadIdx.x;
  __shared__ float e[8][64], al[8][64];
  for (int i = tid; i < 512; i += 256) e[i >> 6][i & 63] = Eq[(q0 + (i >> 6)) * 64 + (i & 63)];
  __syncthreads();
  for (int i = tid; i < 512; i += 256) {
    int qq = i >> 6, k = i & 63;
    float s = 0.f;
    #pragma unroll 8
    for (int d = 0; d < 64; ++d) s += e[qq][d] * W1[d * 64 + k];
    al[qq][k] = s;
  }
  __syncthreads();
  {
    int m = tid >> 6, k = tid & 63;
    const float* src = (m < 2 ? W2 : W3) + (m & 1) * 64 * 64;
    float acc[8] = {0.f, 0.f, 0.f, 0.f, 0.f, 0.f, 0.f, 0.f};
    for (int j = 0; j < 64; ++j) {
      float w = src[j * 64 + k];
      #pragma unroll
      for (int qq = 0; qq < 8; ++qq) acc[qq] += al[qq][j] * w;
    }
    #pragma unroll
    for (int qq = 0; qq < 8; ++qq) T[(q0 + qq) * 256 + m * 64 + k] = acc[qq];
  }
  if (tid < 128) {
    int c = tid;
    float acc[8] = {0.f, 0.f, 0.f, 0.f, 0.f, 0.f, 0.f, 0.f};
    for (int d = 0; d < 64; ++d) {
      float w = Wdiff[d * 128 + c];
      #pragma unroll
      for (int qq = 0; qq < 8; ++qq) acc[qq] += e[qq][d] * w;
    }
    #pragma unroll
    for (int qq = 0; qq < 8; ++qq)
      DIFF[(q0 + qq) * 128 + c] = qmat[(q0 + qq) * 128 + c] * sigm(acc[qq] + bdiff[c]);
  } else if (tid < 136) {
    int qq = tid - 128;
    float s = 0.f;
    for (int d = 0; d < 64; ++d) s += e[qq][d] * Wdisc[d];
    DISCq[q0 + qq] = 5.f * sigm(s + bdisc[0]);
  }
  if (blockIdx.x == 0) {
    __shared__ float alc[2][64];
    if (tid < 128) {
      int cr = tid >> 6, k = tid & 63;
      float s = b1[k];
      for (int d = 0; d < 64; ++d) s += Ec[cr * 64 + d] * W1[(64 + d) * 64 + k];
      alc[cr][k] = s;
    }
    __syncthreads();
    if (tid < 128) {
      int cr = tid >> 6, k = tid & 63;
      float u2a = 0.f, u2b = 0.f, u3a = 0.f, u3b = 0.f;
      for (int j = 0; j < 64; ++j) {
        float a = alc[cr][j];
        u2a += a * W2[j * 64 + k];       u2b += a * W2[(64 + j) * 64 + k];
        u3a += a * W3[j * 64 + k];       u3b += a * W3[(64 + j) * 64 + k];
      }
      Uws[(0 + cr) * 64 + k] = u2a;  Uws[(2 + cr) * 64 + k] = u2b;
      Uws[(4 + cr) * 64 + k] = u3a;  Uws[(6 + cr) * 64 + k] = u3b;
    }
  }
}

// ---------------------------------------------------------------------------
__global__ void pcR(const int* __restrict__ qs, const int* __restrict__ cs,
                    const float* __restrict__ qmat,
                    const float* __restrict__ b2, const float* __restrict__ b3,
                    const float* __restrict__ T, const float* __restrict__ Uws,
                    float* __restrict__ REC) {
  int tid = threadIdx.x;
  for (int i = 0; i < 4; ++i) {
    int bs = blockIdx.x * 4 + i;
    int t  = bs & (SS - 1);
    int q_t = qs[bs];
    float* rec = REC + (size_t)bs * RECF;
    if (tid < 64) {
      int k = tid;
      float v2 = b2[k], v3 = b3[k];
      if (t >= 1) {
        int q1 = qs[bs - 1], c1 = cs[bs - 1];
        v2 += T[q1 * 256 + 64 + k]  + Uws[(2 + c1) * 64 + k];
        v3 += T[q1 * 256 + 192 + k] + Uws[(6 + c1) * 64 + k];
      }
      if (t >= 2) {
        int q2 = qs[bs - 2], c2 = cs[bs - 2];
        v2 += T[q2 * 256 + k]       + Uws[(0 + c2) * 64 + k];
        v3 += T[q2 * 256 + 128 + k] + Uws[(4 + c2) * 64 + k];
      }
      int pp = (k & 15) * 4 + (k >> 4);
      rec[pp] = v2; rec[64 + pp] = v3;
    }
    unsigned long long m = __ballot(qmat[q_t * 128 + tid] > 0.5f);
    int wv = tid >> 6, lane = tid & 63;
    if (lane == 0) {
      rec[128 + wv * 2]     = __uint_as_float((unsigned)m);
      rec[128 + wv * 2 + 1] = __uint_as_float((unsigned)(m >> 32));
    }
  }
}

// ---------------------------------------------------------------------------
__global__ void pcY(const int* __restrict__ qs, const float* __restrict__ qmat,
                    const float* __restrict__ DIFF, const float* __restrict__ DISCq,
                    const float* __restrict__ YP, const float* __restrict__ bab,
                    float* __restrict__ out) {
  int tid = threadIdx.x, lane = tid & 63, wv = tid >> 6;
  const float bab0 = bab[0];
  __shared__ float red[4][2];
  #pragma unroll
  for (int i = 0; i < 4; ++i) {
    int bs = blockIdx.x * 4 + i;
    int t  = bs & (SS - 1);
    float v = 0.f;
    if (t != 0) {
      int q_t = qs[bs];
      float yp = YP[(size_t)bs * 128 + tid];
      float qn = qmat[q_t * 128 + tid] > 0.5f ? 1.f : 0.f;
      v = sigm(yp + bab0) * qn - DIFF[q_t * 128 + tid];
    }
    v += __shfl_xor(v, 32); v += __shfl_xor(v, 16); v += __shfl_xor(v, 8);
    v += __shfl_xor(v, 4);  v += __shfl_xor(v, 2);  v += __shfl_xor(v, 1);
    if (lane == 0) red[i][wv] = v;
  }
  __syncthreads();
  if (tid < 4) {
    int bs = blockIdx.x * 4 + tid;
    int t  = bs & (SS - 1);
    if (t == 0) out[bs] = 0.f;
    else        out[bs] = sigm(DISCq[qs[bs]] * (red[tid][0] + red[tid][1]));
  }
}

// ---------------------------------------------------------------------------
// Main. grid=64, block=256 (4 waves), ONE barrier/step. Wave wv owns c-band
// [32wv,32wv+32) (2 m-tiles). af/acc/ya computed at the TOP of each step from
// h(t-1) (post-barrier, overlapping the up[] chain-top reads) instead of at
// the pre-barrier tail — the lgkmcnt(0) drain no longer waits on them.
__global__ __launch_bounds__(256, 1) __attribute__((amdgpu_waves_per_eu(1, 1)))
void lpkt_main(
    const float* __restrict__ h0,
    const float* __restrict__ W2, const float* __restrict__ W3,
    const float* __restrict__ W4, const float* __restrict__ b4,
    const float* __restrict__ Wab,
    const float* __restrict__ REC, float* __restrict__ YP) {
  __shared__ __align__(16) short hsb[CD * HP2];     // bf16 h (wave-private rows)
  __shared__ __align__(16) short lgb[4 * 64];       // per-wave lg slot (wave-local)
  __shared__ __align__(16) short pkb[4 * 64];       // per-wave pk slot (wave-local)
  __shared__ __align__(16) float up[2][4][2][64];   // u2/u3 partials, dbl-buffered

  const int b    = blockIdx.x;
  const int tid  = threadIdx.x;
  const int lane = tid & 63;
  const int wv   = tid >> 6;       // 0..3
  const int col  = lane & 15;
  const int quad = lane >> 4;
  const int bS   = b * SS;
  const f32x4 zz = {0.f, 0.f, 0.f, 0.f};

  const float* W4a = W4;
  const float* W4b = W4 + 64 * 64;
  const float* W2c = W2 + 128 * 64;
  const float* W3c = W3 + 128 * 64;

  // ---- persistent register fragments (k_eff perm: ke=(p&3)*16+(p>>2)) ----
  bf16x8 bw4[4][2], bwb[4][2], bw2[4][2], bw3[4][2], bwab[2];
  float b4r[4];
  #pragma unroll
  for (int nb = 0; nb < 4; ++nb) {
    #pragma unroll
    for (int half = 0; half < 2; ++half)
      #pragma unroll
      for (int j = 0; j < 8; ++j) {
        int p  = half * 32 + quad * 8 + j;
        int ke = (p & 3) * 16 + (p >> 2);
        int kk = ke * 64 + nb * 16 + col;
        bw4[nb][half][j] = f2bf(W4a[kk]);
        bwb[nb][half][j] = f2bf(W4b[kk]);
        bw2[nb][half][j] = f2bf(W2c[kk]);
        bw3[nb][half][j] = f2bf(W3c[kk]);
      }
    b4r[nb] = b4[nb * 16 + col];
  }
  #pragma unroll
  for (int half = 0; half < 2; ++half)
    #pragma unroll
    for (int j = 0; j < 8; ++j) {
      int p  = half * 32 + quad * 8 + j;
      int ke = (p & 3) * 16 + (p >> 2);
      bwab[half][j] = (col == 0) ? f2bf(Wab[ke]) : (short)0;
    }

  // ---- h init: fp32 regs + bf16 LDS copy ----
  float h2[2][4][4];
  #pragma unroll
  for (int mt = 0; mt < 2; ++mt)
    #pragma unroll
    for (int reg = 0; reg < 4; ++reg) {
      int c = 32 * wv + 16 * mt + 4 * quad + reg;
      #pragma unroll
      for (int n = 0; n < 4; ++n) h2[mt][reg][n] = h0[c * 64 + n * 16 + col];
      store_bf4(&hsb[c * HP2 + col * 4],
                h2[mt][reg][0], h2[mt][reg][1], h2[mt][reg][2], h2[mt][reg][3]);
    }

  // ---- pre-loop: pk0 -> u-partials(up[1]) ----
  unsigned qe_w = __float_as_uint(REC[(size_t)bS * RECF + 128 + wv]);
  {
    float pk[4] = {0.f, 0.f, 0.f, 0.f};
    #pragma unroll
    for (int mt = 0; mt < 2; ++mt)
      #pragma unroll
      for (int reg = 0; reg < 4; ++reg) {
        float q = (float)((qe_w >> (16 * mt + 4 * quad + reg)) & 1u);
        #pragma unroll
        for (int n = 0; n < 4; ++n) pk[n] += q * h2[mt][reg][n];
      }
    #pragma unroll
    for (int n = 0; n < 4; ++n) {
      pk[n] += __shfl_xor(pk[n], 16);
      pk[n] += __shfl_xor(pk[n], 32);
    }
    if (quad == 0) store_bf4(&pkb[wv * 64 + col * 4], pk[0], pk[1], pk[2], pk[3]);
  }
  bf16x8 pf0 = *(const bf16x8*)&pkb[wv * 64 + quad * 8];
  bf16x8 pf1 = *(const bf16x8*)&pkb[wv * 64 + 32 + quad * 8];
  {
    float v2[4], v3[4];
    #pragma unroll
    for (int nb = 0; nb < 4; ++nb) {
      f32x4 a2 = __builtin_amdgcn_mfma_f32_16x16x32_bf16(pf0, bw2[nb][0], zz, 0, 0, 0);
      a2 = __builtin_amdgcn_mfma_f32_16x16x32_bf16(pf1, bw2[nb][1], a2, 0, 0, 0);
      f32x4 a3 = __builtin_amdgcn_mfma_f32_16x16x32_bf16(pf0, bw3[nb][0], zz, 0, 0, 0);
      a3 = __builtin_amdgcn_mfma_f32_16x16x32_bf16(pf1, bw3[nb][1], a3, 0, 0, 0);
      v2[nb] = a2[0]; v3[nb] = a3[0];
    }
    if (quad == 0) {
      *(float4*)&up[1][wv][0][col * 4] = make_float4(v2[0], v2[1], v2[2], v2[3]);
      *(float4*)&up[1][wv][1][col * 4] = make_float4(v3[0], v3[1], v3[2], v3[3]);
    }
  }

  // ---- prefetch pipelines (2 steps ahead) ----
  unsigned qbw[2];
  qbw[1] = __float_as_uint(REC[(size_t)(bS + 1) * RECF + 128 + wv]);
  qbw[0] = __float_as_uint(REC[(size_t)(bS + 2) * RECF + 128 + wv]);
  float4 pb2[2], pb3[2];
  pb2[1] = *(const float4*)&REC[(size_t)(bS + 1) * RECF + col * 4];
  pb3[1] = *(const float4*)&REC[(size_t)(bS + 1) * RECF + 64 + col * 4];
  pb2[0] = *(const float4*)&REC[(size_t)(bS + 2) * RECF + col * 4];
  pb3[0] = *(const float4*)&REC[(size_t)(bS + 2) * RECF + 64 + col * 4];
  BAR();

  for (int t = 1; t < SS; ++t) {
    const int par = t & 1;
    // ===== post-barrier head: af reads of h(t-1) (wave-private, overlap) =====
    bf16x8 af[2][2];
    #pragma unroll
    for (int mt = 0; mt < 2; ++mt) {
      int r = 32 * wv + 16 * mt + col;
      af[mt][0] = *(const bf16x8*)&hsb[r * HP2 + quad * 8];
      af[mt][1] = *(const bf16x8*)&hsb[r * HP2 + 32 + quad * 8];
    }
    // ===== chain-top: u from partials =====
    float4 u2v = pb2[par], u3v = pb3[par];
    {
      float4 a0 = *(const float4*)&up[par][0][0][col * 4];
      float4 a1 = *(const float4*)&up[par][1][0][col * 4];
      float4 a2 = *(const float4*)&up[par][2][0][col * 4];
      float4 a3 = *(const float4*)&up[par][3][0][col * 4];
      float4 c0 = *(const float4*)&up[par][0][1][col * 4];
      float4 c1 = *(const float4*)&up[par][1][1][col * 4];
      float4 c2 = *(const float4*)&up[par][2][1][col * 4];
      float4 c3 = *(const float4*)&up[par][3][1][col * 4];
      u2v.x += a0.x + a1.x + a2.x + a3.x;  u3v.x += c0.x + c1.x + c2.x + c3.x;
      u2v.y += a0.y + a1.y + a2.y + a3.y;  u3v.y += c0.y + c1.y + c2.y + c3.y;
      u2v.z += a0.z + a1.z + a2.z + a3.z;  u3v.z += c0.z + c1.z + c2.z + c3.z;
      u2v.w += a0.w + a1.w + a2.w + a3.w;  u3v.w += c0.w + c1.w + c2.w + c3.w;
    }
    // acc/ya MFMAs from h(t-1): matrix pipe, overlaps the lg/tvv chain
    f32x4 acc[2][4];
    #pragma unroll
    for (int mt = 0; mt < 2; ++mt)
      #pragma unroll
      for (int nb = 0; nb < 4; ++nb) {
        acc[mt][nb] = __builtin_amdgcn_mfma_f32_16x16x32_bf16(af[mt][0], bw4[nb][0], zz, 0, 0, 0);
        acc[mt][nb] = __builtin_amdgcn_mfma_f32_16x16x32_bf16(af[mt][1], bw4[nb][1], acc[mt][nb], 0, 0, 0);
      }
    #pragma unroll
    for (int mt = 0; mt < 2; ++mt) {
      f32x4 ya = __builtin_amdgcn_mfma_f32_16x16x32_bf16(af[mt][0], bwab[0], zz, 0, 0, 0);
      ya = __builtin_amdgcn_mfma_f32_16x16x32_bf16(af[mt][1], bwab[1], ya, 0, 0, 0);
      if (col == 0)
        *(float4*)&YP[((size_t)bS + t - 1) * 128 + 32 * wv + 16 * mt + 4 * quad]
            = make_float4(ya[0], ya[1], ya[2], ya[3]);
    }
    float lg[4];
    lg[0] = sigm(u3v.x) * sigm(2.f * u2v.x);
    lg[1] = sigm(u3v.y) * sigm(2.f * u2v.y);
    lg[2] = sigm(u3v.z) * sigm(2.f * u2v.z);
    lg[3] = sigm(u3v.w) * sigm(2.f * u2v.w);
    if (quad == 0) store_bf4(&lgb[wv * 64 + col * 4], lg[0], lg[1], lg[2], lg[3]);
    // reissue prefetches (latency-tolerant, in flight across BAR)
    unsigned qn_w = qbw[par];
    {
      int tn = (t + 2 < SS) ? t + 2 : SS - 1;
      const float* rn = REC + (size_t)(bS + tn) * RECF;
      qbw[par] = __float_as_uint(rn[128 + wv]);
      pb2[par] = *(const float4*)&rn[col * 4];
      pb3[par] = *(const float4*)&rn[64 + col * 4];
    }
    bf16x8 lf0 = *(const bf16x8*)&lgb[wv * 64 + quad * 8];
    bf16x8 lf1 = *(const bf16x8*)&lgb[wv * 64 + 32 + quad * 8];
    float tvv[4];
    #pragma unroll
    for (int nb = 0; nb < 4; ++nb) {
      f32x4 bb = __builtin_amdgcn_mfma_f32_16x16x32_bf16(lf0, bwb[nb][0], zz, 0, 0, 0);
      bb = __builtin_amdgcn_mfma_f32_16x16x32_bf16(lf1, bwb[nb][1], bb, 0, 0, 0);
      tvv[nb] = bb[0] + b4r[nb];
    }
    // gates + h update + hsb writeback
    #pragma unroll
    for (int mt = 0; mt < 2; ++mt)
      #pragma unroll
      for (int reg = 0; reg < 4; ++reg) {
        int c = 32 * wv + 16 * mt + 4 * quad + reg;
        float qe = (float)((qe_w >> (16 * mt + 4 * quad + reg)) & 1u);
        #pragma unroll
        for (int nb = 0; nb < 4; ++nb) {
          float g = sigm(acc[mt][nb][reg] + tvv[nb]);
          h2[mt][reg][nb] = qe * lg[nb] + g * h2[mt][reg][nb];
        }
        store_bf4(&hsb[c * HP2 + col * 4],
                  h2[mt][reg][0], h2[mt][reg][1], h2[mt][reg][2], h2[mt][reg][3]);
      }
    // pk(t) -> u-partials for step t+1
    {
      float pk[4] = {0.f, 0.f, 0.f, 0.f};
      #pragma unroll
      for (int mt = 0; mt < 2; ++mt)
        #pragma unroll
        for (int reg = 0; reg < 4; ++reg) {
          float q = (float)((qn_w >> (16 * mt + 4 * quad + reg)) & 1u);
          #pragma unroll
          for (int n = 0; n < 4; ++n) pk[n] += q * h2[mt][reg][n];
        }
      #pragma unroll
      for (int n = 0; n < 4; ++n) {
        pk[n] += __shfl_xor(pk[n], 16);
        pk[n] += __shfl_xor(pk[n], 32);
      }
      if (quad == 0) store_bf4(&pkb[wv * 64 + col * 4], pk[0], pk[1], pk[2], pk[3]);
    }
    pf0 = *(const bf16x8*)&pkb[wv * 64 + quad * 8];
    pf1 = *(const bf16x8*)&pkb[wv * 64 + 32 + quad * 8];
    {
      float v2[4], v3[4];
      #pragma unroll
      for (int nb = 0; nb < 4; ++nb) {
        f32x4 a2 = __builtin_amdgcn_mfma_f32_16x16x32_bf16(pf0, bw2[nb][0], zz, 0, 0, 0);
        a2 = __builtin_amdgcn_mfma_f32_16x16x32_bf16(pf1, bw2[nb][1], a2, 0, 0, 0);
        f32x4 a3 = __builtin_amdgcn_mfma_f32_16x16x32_bf16(pf0, bw3[nb][0], zz, 0, 0, 0);
        a3 = __builtin_amdgcn_mfma_f32_16x16x32_bf16(pf1, bw3[nb][1], a3, 0, 0, 0);
        v2[nb] = a2[0]; v3[nb] = a3[0];
      }
      if (quad == 0) {
        *(float4*)&up[par ^ 1][wv][0][col * 4] = make_float4(v2[0], v2[1], v2[2], v2[3]);
        *(float4*)&up[par ^ 1][wv][1][col * 4] = make_float4(v3[0], v3[1], v3[2], v3[3]);
      }
    }
    qe_w = qn_w;
    BAR();
  }

  // ---- epilogue: ability of h(127) -> YP[bS+127] ----
  {
    bf16x8 af0, af1;
    #pragma unroll
    for (int mt = 0; mt < 2; ++mt) {
      int r = 32 * wv + 16 * mt + col;
      af0 = *(const bf16x8*)&hsb[r * HP2 + quad * 8];
      af1 = *(const bf16x8*)&hsb[r * HP2 + 32 + quad * 8];
      f32x4 ya = __builtin_amdgcn_mfma_f32_16x16x32_bf16(af0, bwab[0], zz, 0, 0, 0);
      ya = __builtin_amdgcn_mfma_f32_16x16x32_bf16(af1, bwab[1], ya, 0, 0, 0);
      if (col == 0)
        *(float4*)&YP[((size_t)bS + 127) * 128 + 32 * wv + 16 * mt + 4 * quad]
            = make_float4(ya[0], ya[1], ya[2], ya[3]);
    }
  }
}

// ---------------------------------------------------------------------------
extern "C" void kernel_launch(void* const* d_in, const int* in_sizes, int n_in,
                              void* d_out, int out_size, void* d_ws, size_t ws_size,
                              hipStream_t stream) {
  const int*   qs    = (const int*)d_in[0];
  const int*   cs    = (const int*)d_in[1];
  const float* qmat  = (const float*)d_in[2];
  const float* Eq    = (const float*)d_in[3];
  const float* Ec    = (const float*)d_in[4];
  const float* h0    = (const float*)d_in[5];
  const float* W1    = (const float*)d_in[6];
  const float* b1    = (const float*)d_in[7];
  const float* W2    = (const float*)d_in[8];
  const float* b2    = (const float*)d_in[9];
  const float* W3    = (const float*)d_in[10];
  const float* b3    = (const float*)d_in[11];
  const float* W4    = (const float*)d_in[12];
  const float* b4    = (const float*)d_in[13];
  const float* Wab   = (const float*)d_in[14];
  const float* bab   = (const float*)d_in[15];
  const float* Wdiff = (const float*)d_in[16];
  const float* bdiff = (const float*)d_in[17];
  const float* Wdisc = (const float*)d_in[18];
  const float* bdisc = (const float*)d_in[19];
  float* out = (float*)d_out;

  float* w = (float*)d_ws;
  float* T     = w;                       // 2000*256 = 512000
  float* DIFF  = T + 512000;              // 2000*128 = 256000
  float* DISCq = DIFF + 256000;           // 2000
  float* Uws   = DISCq + 2000;            // 512
  float* REC   = Uws + 512;               // 8192*136 = 1114112
  float* YP    = REC + (size_t)BB * SS * RECF;  // 8192*128 = 1048576

  pcT<<<250, 256, 0, stream>>>(Eq, qmat, W1, W2, W3, Ec, b1, Wdiff, bdiff, Wdisc, bdisc,
                               T, DIFF, DISCq, Uws);
  pcR<<<BB * SS / 4, 128, 0, stream>>>(qs, cs, qmat, b2, b3, T, Uws, REC);
  lpkt_main<<<BB, 256, 0, stream>>>(h0, W2, W3, W4, b4, Wab, REC, YP);
  pcY<<<BB * SS / 4, 128, 0, stream>>>(qs, qmat, DIFF, DISCq, YP, bab, out);
}

// Round 16
// 364.725 us; speedup vs baseline: 1.0385x; 1.0385x over previous
//
#include <hip/hip_runtime.h>

// LPKT forward. B=64, S=128, NQ=2000, C=128, K=64, DE=DC=64.
// R16 (FINAL): revert to R14/R11 — best measured (366 us total, main 247 us,
// reproduced twice). Loop is a verified local optimum: R12 (in-loop compose),
// R13 (shuffle frags), R15 (post-barrier acc) all regressed; pre-barrier tail
// work is free (uniform arrival), post-barrier chain additions cost face value.

constexpr int BB = 64, SS = 128, CD = 128;
constexpr int RECF = 136;   // BASE2p[64]|BASE3p[64]|QBITS[4]|pad
constexpr int HP2  = 72;    // shorts per hsb row (144B)

typedef short bf16x8 __attribute__((ext_vector_type(8)));
typedef float f32x4  __attribute__((ext_vector_type(4)));

// barrier WITHOUT vmcnt drain: orders LDS only, global prefetches stay in flight
#define BAR() asm volatile("s_waitcnt lgkmcnt(0)\ns_barrier" ::: "memory")

__device__ __forceinline__ short f2bf(float x) {
  unsigned u = __builtin_bit_cast(unsigned, x);
  unsigned r = u + 0x7fffu + ((u >> 16) & 1u);
  return (short)(r >> 16);
}
__device__ __forceinline__ unsigned pk2bf(float a, float b) {
  unsigned ua = __builtin_bit_cast(unsigned, a);
  unsigned ub = __builtin_bit_cast(unsigned, b);
  unsigned ra = ua + 0x7fffu + ((ua >> 16) & 1u);
  unsigned rb = ub + 0x7fffu + ((ub >> 16) & 1u);
  return (ra >> 16) | (rb & 0xffff0000u);
}
__device__ __forceinline__ float sigm(float x) {
  return __builtin_amdgcn_rcpf(1.f + __expf(-x));
}
__device__ __forceinline__ void store_bf4(short* p, float a, float b, float c, float d) {
  uint2 v = {pk2bf(a, b), pk2bf(c, d)};
  *(uint2*)p = v;
}

// ---------------------------------------------------------------------------
// pcT: per-question tables, pcK folded in via associativity:
//   al_q = Eq[q] @ W1[0:64]           (no bias; bias lives in U)
//   T[q][m*64+k] = al_q @ slab_m      (m: W2a,W2b,W3a,W3b)
// block 0 additionally computes Uws (correctness-side vectors, bias included).
__global__ void pcT(const float* __restrict__ Eq, const float* __restrict__ qmat,
                    const float* __restrict__ W1, const float* __restrict__ W2,
                    const float* __restrict__ W3, const float* __restrict__ Ec,
                    const float* __restrict__ b1,
                    const float* __restrict__ Wdiff, const float* __restrict__ bdiff,
                    const float* __restrict__ Wdisc, const float* __restrict__ bdisc,
                    float* __restrict__ T, float* __restrict__ DIFF,
                    float* __restrict__ DISCq, float* __restrict__ Uws) {
  int q0 = blockIdx.x * 8, tid = threadIdx.x;
  __shared__ float e[8][64], al[8][64];
  for (int i = tid; i < 512; i += 256) e[i >> 6][i & 63] = Eq[(q0 + (i >> 6)) * 64 + (i & 63)];
  __syncthreads();
  for (int i = tid; i < 512; i += 256) {
    int qq = i >> 6, k = i & 63;
    float s = 0.f;
    #pragma unroll 8
    for (int d = 0; d < 64; ++d) s += e[qq][d] * W1[d * 64 + k];
    al[qq][k] = s;
  }
  __syncthreads();
  {
    int m = tid >> 6, k = tid & 63;
    const float* src = (m < 2 ? W2 : W3) + (m & 1) * 64 * 64;
    float acc[8] = {0.f, 0.f, 0.f, 0.f, 0.f, 0.f, 0.f, 0.f};
    for (int j = 0; j < 64; ++j) {
      float w = src[j * 64 + k];
      #pragma unroll
      for (int qq = 0; qq < 8; ++qq) acc[qq] += al[qq][j] * w;
    }
    #pragma unroll
    for (int qq = 0; qq < 8; ++qq) T[(q0 + qq) * 256 + m * 64 + k] = acc[qq];
  }
  if (tid < 128) {
    int c = tid;
    float acc[8] = {0.f, 0.f, 0.f, 0.f, 0.f, 0.f, 0.f, 0.f};
    for (int d = 0; d < 64; ++d) {
      float w = Wdiff[d * 128 + c];
      #pragma unroll
      for (int qq = 0; qq < 8; ++qq) acc[qq] += e[qq][d] * w;
    }
    #pragma unroll
    for (int qq = 0; qq < 8; ++qq)
      DIFF[(q0 + qq) * 128 + c] = qmat[(q0 + qq) * 128 + c] * sigm(acc[qq] + bdiff[c]);
  } else if (tid < 136) {
    int qq = tid - 128;
    float s = 0.f;
    for (int d = 0; d < 64; ++d) s += e[qq][d] * Wdisc[d];
    DISCq[q0 + qq] = 5.f * sigm(s + bdisc[0]);
  }
  if (blockIdx.x == 0) {
    __shared__ float alc[2][64];
    if (tid < 128) {
      int cr = tid >> 6, k = tid & 63;
      float s = b1[k];
      for (int d = 0; d < 64; ++d) s += Ec[cr * 64 + d] * W1[(64 + d) * 64 + k];
      alc[cr][k] = s;
    }
    __syncthreads();
    if (tid < 128) {
      int cr = tid >> 6, k = tid & 63;
      float u2a = 0.f, u2b = 0.f, u3a = 0.f, u3b = 0.f;
      for (int j = 0; j < 64; ++j) {
        float a = alc[cr][j];
        u2a += a * W2[j * 64 + k];       u2b += a * W2[(64 + j) * 64 + k];
        u3a += a * W3[j * 64 + k];       u3b += a * W3[(64 + j) * 64 + k];
      }
      Uws[(0 + cr) * 64 + k] = u2a;  Uws[(2 + cr) * 64 + k] = u2b;
      Uws[(4 + cr) * 64 + k] = u3a;  Uws[(6 + cr) * 64 + k] = u3b;
    }
  }
}

// ---------------------------------------------------------------------------
__global__ void pcR(const int* __restrict__ qs, const int* __restrict__ cs,
                    const float* __restrict__ qmat,
                    const float* __restrict__ b2, const float* __restrict__ b3,
                    const float* __restrict__ T, const float* __restrict__ Uws,
                    float* __restrict__ REC) {
  int tid = threadIdx.x;
  for (int i = 0; i < 4; ++i) {
    int bs = blockIdx.x * 4 + i;
    int t  = bs & (SS - 1);
    int q_t = qs[bs];
    float* rec = REC + (size_t)bs * RECF;
    if (tid < 64) {
      int k = tid;
      float v2 = b2[k], v3 = b3[k];
      if (t >= 1) {
        int q1 = qs[bs - 1], c1 = cs[bs - 1];
        v2 += T[q1 * 256 + 64 + k]  + Uws[(2 + c1) * 64 + k];
        v3 += T[q1 * 256 + 192 + k] + Uws[(6 + c1) * 64 + k];
      }
      if (t >= 2) {
        int q2 = qs[bs - 2], c2 = cs[bs - 2];
        v2 += T[q2 * 256 + k]       + Uws[(0 + c2) * 64 + k];
        v3 += T[q2 * 256 + 128 + k] + Uws[(4 + c2) * 64 + k];
      }
      int pp = (k & 15) * 4 + (k >> 4);
      rec[pp] = v2; rec[64 + pp] = v3;
    }
    unsigned long long m = __ballot(qmat[q_t * 128 + tid] > 0.5f);
    int wv = tid >> 6, lane = tid & 63;
    if (lane == 0) {
      rec[128 + wv * 2]     = __uint_as_float((unsigned)m);
      rec[128 + wv * 2 + 1] = __uint_as_float((unsigned)(m >> 32));
    }
  }
}

// ---------------------------------------------------------------------------
__global__ void pcY(const int* __restrict__ qs, const float* __restrict__ qmat,
                    const float* __restrict__ DIFF, const float* __restrict__ DISCq,
                    const float* __restrict__ YP, const float* __restrict__ bab,
                    float* __restrict__ out) {
  int tid = threadIdx.x, lane = tid & 63, wv = tid >> 6;
  const float bab0 = bab[0];
  __shared__ float red[4][2];
  #pragma unroll
  for (int i = 0; i < 4; ++i) {
    int bs = blockIdx.x * 4 + i;
    int t  = bs & (SS - 1);
    float v = 0.f;
    if (t != 0) {
      int q_t = qs[bs];
      float yp = YP[(size_t)bs * 128 + tid];
      float qn = qmat[q_t * 128 + tid] > 0.5f ? 1.f : 0.f;
      v = sigm(yp + bab0) * qn - DIFF[q_t * 128 + tid];
    }
    v += __shfl_xor(v, 32); v += __shfl_xor(v, 16); v += __shfl_xor(v, 8);
    v += __shfl_xor(v, 4);  v += __shfl_xor(v, 2);  v += __shfl_xor(v, 1);
    if (lane == 0) red[i][wv] = v;
  }
  __syncthreads();
  if (tid < 4) {
    int bs = blockIdx.x * 4 + tid;
    int t  = bs & (SS - 1);
    if (t == 0) out[bs] = 0.f;
    else        out[bs] = sigm(DISCq[qs[bs]] * (red[tid][0] + red[tid][1]));
  }
}

// ---------------------------------------------------------------------------
// Main. grid=64, block=256 (4 waves), ONE barrier/step. Wave wv owns c-band
// [32wv,32wv+32) (2 m-tiles). up[parity][wave][u2/u3][64]: per-wave u-partials
// written pre-barrier (MFMA on pk_w), summed post-barrier. acc (gate GEMM of
// fresh h) carried across the barrier in registers (pre-barrier tail is free:
// uniform across waves — R15 showed moving it post-barrier costs +5%).
__global__ __launch_bounds__(256, 1) __attribute__((amdgpu_waves_per_eu(1, 1)))
void lpkt_main(
    const float* __restrict__ h0,
    const float* __restrict__ W2, const float* __restrict__ W3,
    const float* __restrict__ W4, const float* __restrict__ b4,
    const float* __restrict__ Wab,
    const float* __restrict__ REC, float* __restrict__ YP) {
  __shared__ __align__(16) short hsb[CD * HP2];     // bf16 h (wave-private rows)
  __shared__ __align__(16) short lgb[4 * 64];       // per-wave lg slot (wave-local)
  __shared__ __align__(16) short pkb[4 * 64];       // per-wave pk slot (wave-local)
  __shared__ __align__(16) float up[2][4][2][64];   // u2/u3 partials, dbl-buffered

  const int b    = blockIdx.x;
  const int tid  = threadIdx.x;
  const int lane = tid & 63;
  const int wv   = tid >> 6;       // 0..3
  const int col  = lane & 15;
  const int quad = lane >> 4;
  const int bS   = b * SS;
  const f32x4 zz = {0.f, 0.f, 0.f, 0.f};

  const float* W4a = W4;
  const float* W4b = W4 + 64 * 64;
  const float* W2c = W2 + 128 * 64;
  const float* W3c = W3 + 128 * 64;

  // ---- persistent register fragments (k_eff perm: ke=(p&3)*16+(p>>2)) ----
  bf16x8 bw4[4][2], bwb[4][2], bw2[4][2], bw3[4][2], bwab[2];
  float b4r[4];
  #pragma unroll
  for (int nb = 0; nb < 4; ++nb) {
    #pragma unroll
    for (int half = 0; half < 2; ++half)
      #pragma unroll
      for (int j = 0; j < 8; ++j) {
        int p  = half * 32 + quad * 8 + j;
        int ke = (p & 3) * 16 + (p >> 2);
        int kk = ke * 64 + nb * 16 + col;
        bw4[nb][half][j] = f2bf(W4a[kk]);
        bwb[nb][half][j] = f2bf(W4b[kk]);
        bw2[nb][half][j] = f2bf(W2c[kk]);
        bw3[nb][half][j] = f2bf(W3c[kk]);
      }
    b4r[nb] = b4[nb * 16 + col];
  }
  #pragma unroll
  for (int half = 0; half < 2; ++half)
    #pragma unroll
    for (int j = 0; j < 8; ++j) {
      int p  = half * 32 + quad * 8 + j;
      int ke = (p & 3) * 16 + (p >> 2);
      bwab[half][j] = (col == 0) ? f2bf(Wab[ke]) : (short)0;
    }

  // ---- h init: fp32 regs + bf16 LDS copy ----
  float h2[2][4][4];
  #pragma unroll
  for (int mt = 0; mt < 2; ++mt)
    #pragma unroll
    for (int reg = 0; reg < 4; ++reg) {
      int c = 32 * wv + 16 * mt + 4 * quad + reg;
      #pragma unroll
      for (int n = 0; n < 4; ++n) h2[mt][reg][n] = h0[c * 64 + n * 16 + col];
      store_bf4(&hsb[c * HP2 + col * 4],
                h2[mt][reg][0], h2[mt][reg][1], h2[mt][reg][2], h2[mt][reg][3]);
    }

  // ---- pre-loop: pk0 -> u-partials(up[1]); acc = G(h0); af(h0) ----
  unsigned qe_w = __float_as_uint(REC[(size_t)bS * RECF + 128 + wv]);
  {
    float pk[4] = {0.f, 0.f, 0.f, 0.f};
    #pragma unroll
    for (int mt = 0; mt < 2; ++mt)
      #pragma unroll
      for (int reg = 0; reg < 4; ++reg) {
        float q = (float)((qe_w >> (16 * mt + 4 * quad + reg)) & 1u);
        #pragma unroll
        for (int n = 0; n < 4; ++n) pk[n] += q * h2[mt][reg][n];
      }
    #pragma unroll
    for (int n = 0; n < 4; ++n) {
      pk[n] += __shfl_xor(pk[n], 16);
      pk[n] += __shfl_xor(pk[n], 32);
    }
    if (quad == 0) store_bf4(&pkb[wv * 64 + col * 4], pk[0], pk[1], pk[2], pk[3]);
  }
  bf16x8 pf0 = *(const bf16x8*)&pkb[wv * 64 + quad * 8];
  bf16x8 pf1 = *(const bf16x8*)&pkb[wv * 64 + 32 + quad * 8];
  {
    float v2[4], v3[4];
    #pragma unroll
    for (int nb = 0; nb < 4; ++nb) {
      f32x4 a2 = __builtin_amdgcn_mfma_f32_16x16x32_bf16(pf0, bw2[nb][0], zz, 0, 0, 0);
      a2 = __builtin_amdgcn_mfma_f32_16x16x32_bf16(pf1, bw2[nb][1], a2, 0, 0, 0);
      f32x4 a3 = __builtin_amdgcn_mfma_f32_16x16x32_bf16(pf0, bw3[nb][0], zz, 0, 0, 0);
      a3 = __builtin_amdgcn_mfma_f32_16x16x32_bf16(pf1, bw3[nb][1], a3, 0, 0, 0);
      v2[nb] = a2[0]; v3[nb] = a3[0];
    }
    if (quad == 0) {
      *(float4*)&up[1][wv][0][col * 4] = make_float4(v2[0], v2[1], v2[2], v2[3]);
      *(float4*)&up[1][wv][1][col * 4] = make_float4(v3[0], v3[1], v3[2], v3[3]);
    }
  }
  bf16x8 af[2][2];
  #pragma unroll
  for (int mt = 0; mt < 2; ++mt) {
    int r = 32 * wv + 16 * mt + col;
    af[mt][0] = *(const bf16x8*)&hsb[r * HP2 + quad * 8];
    af[mt][1] = *(const bf16x8*)&hsb[r * HP2 + 32 + quad * 8];
  }
  f32x4 acc[2][4];
  #pragma unroll
  for (int mt = 0; mt < 2; ++mt)
    #pragma unroll
    for (int nb = 0; nb < 4; ++nb) {
      acc[mt][nb] = __builtin_amdgcn_mfma_f32_16x16x32_bf16(af[mt][0], bw4[nb][0], zz, 0, 0, 0);
      acc[mt][nb] = __builtin_amdgcn_mfma_f32_16x16x32_bf16(af[mt][1], bw4[nb][1], acc[mt][nb], 0, 0, 0);
    }

  // ---- prefetch pipelines (2 steps ahead) ----
  unsigned qbw[2];
  qbw[1] = __float_as_uint(REC[(size_t)(bS + 1) * RECF + 128 + wv]);
  qbw[0] = __float_as_uint(REC[(size_t)(bS + 2) * RECF + 128 + wv]);
  float4 pb2[2], pb3[2];
  pb2[1] = *(const float4*)&REC[(size_t)(bS + 1) * RECF + col * 4];
  pb3[1] = *(const float4*)&REC[(size_t)(bS + 1) * RECF + 64 + col * 4];
  pb2[0] = *(const float4*)&REC[(size_t)(bS + 2) * RECF + col * 4];
  pb3[0] = *(const float4*)&REC[(size_t)(bS + 2) * RECF + 64 + col * 4];
  BAR();

  for (int t = 1; t < SS; ++t) {
    const int par = t & 1;
    // ===== post-barrier critical chain =====
    float4 u2v = pb2[par], u3v = pb3[par];
    {
      float4 a0 = *(const float4*)&up[par][0][0][col * 4];
      float4 a1 = *(const float4*)&up[par][1][0][col * 4];
      float4 a2 = *(const float4*)&up[par][2][0][col * 4];
      float4 a3 = *(const float4*)&up[par][3][0][col * 4];
      float4 c0 = *(const float4*)&up[par][0][1][col * 4];
      float4 c1 = *(const float4*)&up[par][1][1][col * 4];
      float4 c2 = *(const float4*)&up[par][2][1][col * 4];
      float4 c3 = *(const float4*)&up[par][3][1][col * 4];
      u2v.x += a0.x + a1.x + a2.x + a3.x;  u3v.x += c0.x + c1.x + c2.x + c3.x;
      u2v.y += a0.y + a1.y + a2.y + a3.y;  u3v.y += c0.y + c1.y + c2.y + c3.y;
      u2v.z += a0.z + a1.z + a2.z + a3.z;  u3v.z += c0.z + c1.z + c2.z + c3.z;
      u2v.w += a0.w + a1.w + a2.w + a3.w;  u3v.w += c0.w + c1.w + c2.w + c3.w;
    }
    float lg[4];
    lg[0] = sigm(u3v.x) * sigm(2.f * u2v.x);
    lg[1] = sigm(u3v.y) * sigm(2.f * u2v.y);
    lg[2] = sigm(u3v.z) * sigm(2.f * u2v.z);
    lg[3] = sigm(u3v.w) * sigm(2.f * u2v.w);
    if (quad == 0) store_bf4(&lgb[wv * 64 + col * 4], lg[0], lg[1], lg[2], lg[3]);
    // reissue prefetches (latency-tolerant, in flight across BAR)
    unsigned qn_w = qbw[par];
    {
      int tn = (t + 2 < SS) ? t + 2 : SS - 1;
      const float* rn = REC + (size_t)(bS + tn) * RECF;
      qbw[par] = __float_as_uint(rn[128 + wv]);
      pb2[par] = *(const float4*)&rn[col * 4];
      pb3[par] = *(const float4*)&rn[64 + col * 4];
    }
    bf16x8 lf0 = *(const bf16x8*)&lgb[wv * 64 + quad * 8];
    bf16x8 lf1 = *(const bf16x8*)&lgb[wv * 64 + 32 + quad * 8];
    float tvv[4];
    #pragma unroll
    for (int nb = 0; nb < 4; ++nb) {
      f32x4 bb = __builtin_amdgcn_mfma_f32_16x16x32_bf16(lf0, bwb[nb][0], zz, 0, 0, 0);
      bb = __builtin_amdgcn_mfma_f32_16x16x32_bf16(lf1, bwb[nb][1], bb, 0, 0, 0);
      tvv[nb] = bb[0] + b4r[nb];
    }
    // gates + h update + hsb writeback
    #pragma unroll
    for (int mt = 0; mt < 2; ++mt)
      #pragma unroll
      for (int reg = 0; reg < 4; ++reg) {
        int c = 32 * wv + 16 * mt + 4 * quad + reg;
        float qe = (float)((qe_w >> (16 * mt + 4 * quad + reg)) & 1u);
        #pragma unroll
        for (int nb = 0; nb < 4; ++nb) {
          float g = sigm(acc[mt][nb][reg] + tvv[nb]);
          h2[mt][reg][nb] = qe * lg[nb] + g * h2[mt][reg][nb];
        }
        store_bf4(&hsb[c * HP2 + col * 4],
                  h2[mt][reg][0], h2[mt][reg][1], h2[mt][reg][2], h2[mt][reg][3]);
      }
    // pk(t) -> u-partials for step t+1
    {
      float pk[4] = {0.f, 0.f, 0.f, 0.f};
      #pragma unroll
      for (int mt = 0; mt < 2; ++mt)
        #pragma unroll
        for (int reg = 0; reg < 4; ++reg) {
          float q = (float)((qn_w >> (16 * mt + 4 * quad + reg)) & 1u);
          #pragma unroll
          for (int n = 0; n < 4; ++n) pk[n] += q * h2[mt][reg][n];
        }
      #pragma unroll
      for (int n = 0; n < 4; ++n) {
        pk[n] += __shfl_xor(pk[n], 16);
        pk[n] += __shfl_xor(pk[n], 32);
      }
      if (quad == 0) store_bf4(&pkb[wv * 64 + col * 4], pk[0], pk[1], pk[2], pk[3]);
    }
    pf0 = *(const bf16x8*)&pkb[wv * 64 + quad * 8];
    pf1 = *(const bf16x8*)&pkb[wv * 64 + 32 + quad * 8];
    {
      float v2[4], v3[4];
      #pragma unroll
      for (int nb = 0; nb < 4; ++nb) {
        f32x4 a2 = __builtin_amdgcn_mfma_f32_16x16x32_bf16(pf0, bw2[nb][0], zz, 0, 0, 0);
        a2 = __builtin_amdgcn_mfma_f32_16x16x32_bf16(pf1, bw2[nb][1], a2, 0, 0, 0);
        f32x4 a3 = __builtin_amdgcn_mfma_f32_16x16x32_bf16(pf0, bw3[nb][0], zz, 0, 0, 0);
        a3 = __builtin_amdgcn_mfma_f32_16x16x32_bf16(pf1, bw3[nb][1], a3, 0, 0, 0);
        v2[nb] = a2[0]; v3[nb] = a3[0];
      }
      if (quad == 0) {
        *(float4*)&up[par ^ 1][wv][0][col * 4] = make_float4(v2[0], v2[1], v2[2], v2[3]);
        *(float4*)&up[par ^ 1][wv][1][col * 4] = make_float4(v3[0], v3[1], v3[2], v3[3]);
      }
    }
    // af of fresh h; G for next step; ability -> YP[bS+t]
    #pragma unroll
    for (int mt = 0; mt < 2; ++mt) {
      int r = 32 * wv + 16 * mt + col;
      af[mt][0] = *(const bf16x8*)&hsb[r * HP2 + quad * 8];
      af[mt][1] = *(const bf16x8*)&hsb[r * HP2 + 32 + quad * 8];
    }
    #pragma unroll
    for (int mt = 0; mt < 2; ++mt)
      #pragma unroll
      for (int nb = 0; nb < 4; ++nb) {
        acc[mt][nb] = __builtin_amdgcn_mfma_f32_16x16x32_bf16(af[mt][0], bw4[nb][0], zz, 0, 0, 0);
        acc[mt][nb] = __builtin_amdgcn_mfma_f32_16x16x32_bf16(af[mt][1], bw4[nb][1], acc[mt][nb], 0, 0, 0);
      }
    #pragma unroll
    for (int mt = 0; mt < 2; ++mt) {
      f32x4 ya = __builtin_amdgcn_mfma_f32_16x16x32_bf16(af[mt][0], bwab[0], zz, 0, 0, 0);
      ya = __builtin_amdgcn_mfma_f32_16x16x32_bf16(af[mt][1], bwab[1], ya, 0, 0, 0);
      if (col == 0)
        *(float4*)&YP[((size_t)bS + t) * 128 + 32 * wv + 16 * mt + 4 * quad]
            = make_float4(ya[0], ya[1], ya[2], ya[3]);
    }
    qe_w = qn_w;
    BAR();
  }
}

// ---------------------------------------------------------------------------
extern "C" void kernel_launch(void* const* d_in, const int* in_sizes, int n_in,
                              void* d_out, int out_size, void* d_ws, size_t ws_size,
                              hipStream_t stream) {
  const int*   qs    = (const int*)d_in[0];
  const int*   cs    = (const int*)d_in[1];
  const float* qmat  = (const float*)d_in[2];
  const float* Eq    = (const float*)d_in[3];
  const float* Ec    = (const float*)d_in[4];
  const float* h0    = (const float*)d_in[5];
  const float* W1    = (const float*)d_in[6];
  const float* b1    = (const float*)d_in[7];
  const float* W2    = (const float*)d_in[8];
  const float* b2    = (const float*)d_in[9];
  const float* W3    = (const float*)d_in[10];
  const float* b3    = (const float*)d_in[11];
  const float* W4    = (const float*)d_in[12];
  const float* b4    = (const float*)d_in[13];
  const float* Wab   = (const float*)d_in[14];
  const float* bab   = (const float*)d_in[15];
  const float* Wdiff = (const float*)d_in[16];
  const float* bdiff = (const float*)d_in[17];
  const float* Wdisc = (const float*)d_in[18];
  const float* bdisc = (const float*)d_in[19];
  float* out = (float*)d_out;

  float* w = (float*)d_ws;
  float* T     = w;                       // 2000*256 = 512000
  float* DIFF  = T + 512000;              // 2000*128 = 256000
  float* DISCq = DIFF + 256000;           // 2000
  float* Uws   = DISCq + 2000;            // 512
  float* REC   = Uws + 512;               // 8192*136 = 1114112
  float* YP    = REC + (size_t)BB * SS * RECF;  // 8192*128 = 1048576

  pcT<<<250, 256, 0, stream>>>(Eq, qmat, W1, W2, W3, Ec, b1, Wdiff, bdiff, Wdisc, bdisc,
                               T, DIFF, DISCq, Uws);
  pcR<<<BB * SS / 4, 128, 0, stream>>>(qs, cs, qmat, b2, b3, T, Uws, REC);
  lpkt_main<<<BB, 256, 0, stream>>>(h0, W2, W3, W4, b4, Wab, REC, YP);
  pcY<<<BB * SS / 4, 128, 0, stream>>>(qs, qmat, DIFF, DISCq, YP, bab, out);
}